// Round 23
// baseline (133.425 us; speedup 1.0000x reference)
//
#include <hip/hip_runtime.h>
#include <hip/hip_bf16.h>

typedef __attribute__((ext_vector_type(8))) short short8;
typedef __attribute__((ext_vector_type(4))) short short4v;
typedef __attribute__((ext_vector_type(4))) float f32x4;

#define MFMA16(a, b, c) __builtin_amdgcn_mfma_f32_16x16x32_bf16(a, b, c, 0, 0, 0)
#define EXP2F(x) __builtin_amdgcn_exp2f(x)
// Q pre-scale: 1/sqrt(256) * log2(e) -> scores emerge in the exp2 domain
#define QSCALE 0.09016844005556021f

// round-to-nearest-even f32 -> bf16 bit pattern
__device__ __forceinline__ short f2bf(float f) {
    union { float f; unsigned u; } v; v.f = f;
    unsigned r = v.u + 0x7fffu + ((v.u >> 16) & 1u);
    return (short)(r >> 16);
}
__device__ __forceinline__ unsigned pack2(float lo, float hi) {
    return ((unsigned)(unsigned short)f2bf(hi) << 16) |
           (unsigned)(unsigned short)f2bf(lo);
}
// async global->LDS, 16B/lane; LDS dest = wave-uniform base + lane*16
__device__ __forceinline__ void gload16(const void* g, void* lds) {
    __builtin_amdgcn_global_load_lds(
        (const __attribute__((address_space(1))) unsigned int*)g,
        (__attribute__((address_space(3))) unsigned int*)lds, 16, 0, 0);
}

// ---------------------------------------------------------------------------
// Kernel 0a (fallback): convert [Wq;Wk;Wv] (768x256 f32) to bf16.
// ---------------------------------------------------------------------------
__global__ __launch_bounds__(256) void wconv(
    const float* __restrict__ Wq, const float* __restrict__ Wk,
    const float* __restrict__ Wv, short* __restrict__ Wb)
{
    int e = (blockIdx.x * 256 + threadIdx.x) * 8;
    const float* p = (e < 65536) ? (Wq + e)
                   : (e < 131072) ? (Wk + (e - 65536))
                                  : (Wv + (e - 131072));
    float4 a = *(const float4*)p;
    float4 b = *(const float4*)(p + 4);
    short8 h = { f2bf(a.x), f2bf(a.y), f2bf(a.z), f2bf(a.w),
                 f2bf(b.x), f2bf(b.y), f2bf(b.z), f2bf(b.w) };
    *(short8*)(Wb + e) = h;
}

// ---------------------------------------------------------------------------
// Kernel 0b (fast path): convert W (768x256) AND x (16384x256) f32 -> bf16.
// ---------------------------------------------------------------------------
__global__ __launch_bounds__(256) void conv2(
    const float* __restrict__ Wq, const float* __restrict__ Wk,
    const float* __restrict__ Wv, const float* __restrict__ x,
    short* __restrict__ Wb, short* __restrict__ xb)
{
    const int bid = blockIdx.x;
    if (bid < 96) {
        int e = (bid * 256 + threadIdx.x) * 8;
        const float* p = (e < 65536) ? (Wq + e)
                       : (e < 131072) ? (Wk + (e - 65536))
                                      : (Wv + (e - 131072));
        float4 a = *(const float4*)p;
        float4 b = *(const float4*)(p + 4);
        short8 h = { f2bf(a.x), f2bf(a.y), f2bf(a.z), f2bf(a.w),
                     f2bf(b.x), f2bf(b.y), f2bf(b.z), f2bf(b.w) };
        *(short8*)(Wb + e) = h;
    } else {
        int e = ((bid - 96) * 256 + threadIdx.x) * 8;
        float4 a = *(const float4*)(x + e);
        float4 b = *(const float4*)(x + e + 4);
        short8 h = { f2bf(a.x), f2bf(a.y), f2bf(a.z), f2bf(a.w),
                     f2bf(b.x), f2bf(b.y), f2bf(b.z), f2bf(b.w) };
        *(short8*)(xb + e) = h;
    }
}

// ---------------------------------------------------------------------------
// Kernel 1a (fallback): QKV projection (Q pre-scaled by QSCALE).
// ---------------------------------------------------------------------------
__global__ __launch_bounds__(256) void qkv_proj(
    const float* __restrict__ x, const short* __restrict__ Wb,
    const float* __restrict__ bq, const float* __restrict__ bk,
    const float* __restrict__ bv,
    short* __restrict__ Qb, short* __restrict__ Kb, short* __restrict__ VTg)
{
    __shared__ short xs[64 * 264];
    __shared__ short wsS[64 * 264];

    const int tid = threadIdx.x;
    const int wid = tid >> 6;
    const int l   = tid & 63;
    const int l15 = l & 15, lg = l >> 4;
    const int r0  = blockIdx.x * 64;
    const int cg  = blockIdx.y;

    {
        const float4* src = (const float4*)(x + (size_t)r0 * 256);
        #pragma unroll
        for (int p = 0; p < 16; ++p) {
            float4 v = src[p * 256 + tid];
            int idx = (p * 256 + tid) * 4;
            int row = idx >> 8, col = idx & 255;
            short4v h = { f2bf(v.x), f2bf(v.y), f2bf(v.z), f2bf(v.w) };
            *(short4v*)&xs[row * 264 + col] = h;
        }
    }

    short8 wreg[8];
    {
        const short8* wsrc = (const short8*)(Wb + (size_t)(cg * 3) * 64 * 256);
        #pragma unroll
        for (int p = 0; p < 8; ++p) wreg[p] = wsrc[p * 256 + tid];
    }
    __syncthreads();

    short8 afr[8];
    {
        const int arow = wid * 16 + l15;
        #pragma unroll
        for (int ks = 0; ks < 8; ++ks)
            afr[ks] = *(const short8*)&xs[arow * 264 + ks * 32 + lg * 8];
    }

    const float* bm[3] = { bq, bk, bv };

    for (int c = 0; c < 3; ++c) {
        const int gc  = cg * 3 + c;
        const int m   = gc >> 2;
        const int wr0 = (gc & 3) * 64;

        #pragma unroll
        for (int p = 0; p < 8; ++p) {
            int idx8 = p * 256 + tid;
            int row = idx8 >> 5, col = (idx8 & 31) * 8;
            *(short8*)&wsS[row * 264 + col] = wreg[p];
        }
        __syncthreads();

        if (c < 2) {
            const short8* wsrc =
                (const short8*)(Wb + (size_t)(gc + 1) * 64 * 256);
            #pragma unroll
            for (int p = 0; p < 8; ++p) wreg[p] = wsrc[p * 256 + tid];
        }

        f32x4 acc[4] = {};
        #pragma unroll
        for (int n = 0; n < 4; ++n) {
            const short* kr = &wsS[(n * 16 + l15) * 264 + lg * 8];
            #pragma unroll
            for (int ks = 0; ks < 8; ++ks) {
                short8 bfr = *(const short8*)(kr + ks * 32);
                acc[n] = MFMA16(afr[ks], bfr, acc[n]);
            }
        }

        const int rowbase = r0 + wid * 16 + (lg << 2);
        #pragma unroll
        for (int n = 0; n < 4; ++n) {
            const int col   = wr0 + n * 16 + l15;
            const float bias = bm[m][col];
            #pragma unroll
            for (int j = 0; j < 4; ++j) {
                const int grow = rowbase + j;
                float ov = acc[n][j] + bias;
                if (m == 0) ov *= QSCALE;         // Q pre-scale (exp2 domain)
                short hv = f2bf(ov);
                if (m == 0)      Qb[(size_t)grow * 256 + col] = hv;
                else if (m == 1) Kb[(size_t)grow * 256 + col] = hv;
                else {
                    int bb = grow >> 12, tt = grow & 4095;
                    VTg[(size_t)bb * (256 * 4096) + (size_t)col * 4096 + tt] = hv;
                }
            }
        }
        __syncthreads();
    }
}

// ---------------------------------------------------------------------------
// Kernel 1b (fast path): QKV projection with DMA staging (Q pre-scaled).
// ---------------------------------------------------------------------------
__global__ __launch_bounds__(256, 2) void qkv_proj2(
    const short* __restrict__ xb, const short* __restrict__ Wb,
    const float* __restrict__ bq, const float* __restrict__ bk,
    const float* __restrict__ bv,
    short* __restrict__ Qb, short* __restrict__ Kb, short* __restrict__ VTg)
{
    // [0,32768)     xs: 64 rows x 512B, 16B slot s stored at s^(row&15)
    // [32768,65536) ws: same layout, current W chunk
    __shared__ __attribute__((aligned(16))) char SM[65536];

    const int tid = threadIdx.x;
    const int wid = tid >> 6;
    const int l   = tid & 63;
    const int l15 = l & 15, lg = l >> 4;
    const int r0  = blockIdx.x * 64;
    const int cg  = blockIdx.y;

    // DMA x tile (32KB): 8 instr/thread
    {
        const short* gx = xb + (size_t)r0 * 256;
        #pragma unroll
        for (int inst = 0; inst < 8; ++inst) {
            int off  = inst * 4096 + wid * 1024 + l * 16;   // linear dest byte
            int row  = off >> 9;
            int slot = ((off >> 4) & 31) ^ (row & 15);      // inverse swizzle
            gload16(gx + row * 256 + slot * 8, SM + inst * 4096 + wid * 1024);
        }
    }
    // DMA W chunk c into ws
    auto stageW = [&](int c) {
        if (c >= 3) return;
        const short* gW = Wb + (size_t)(cg * 3 + c) * 64 * 256;
        #pragma unroll
        for (int inst = 0; inst < 8; ++inst) {
            int off  = inst * 4096 + wid * 1024 + l * 16;
            int row  = off >> 9;
            int slot = ((off >> 4) & 31) ^ (row & 15);
            gload16(gW + row * 256 + slot * 8,
                    SM + 32768 + inst * 4096 + wid * 1024);
        }
    };
    stageW(0);

    asm volatile("s_waitcnt vmcnt(0)" ::: "memory");
    __syncthreads();

    // A-fragments once (full K=256 resident), attn-verified slot formula
    short8 afr[8];
    {
        const int arow = wid * 16 + l15;
        #pragma unroll
        for (int ks = 0; ks < 8; ++ks) {
            const int slot = (ks * 4 + lg) ^ l15;
            afr[ks] = *(const short8*)(SM + arow * 512 + slot * 16);
        }
    }

    const float* bm[3] = { bq, bk, bv };

    for (int c = 0; c < 3; ++c) {
        const int gc  = cg * 3 + c;
        const int m   = gc >> 2;
        const int wr0 = (gc & 3) * 64;

        f32x4 acc[4] = {};
        #pragma unroll
        for (int n = 0; n < 4; ++n) {
            const int brow = n * 16 + l15;
            #pragma unroll
            for (int ks = 0; ks < 8; ++ks) {
                const int slot = (ks * 4 + lg) ^ l15;
                short8 bfr = *(const short8*)(SM + 32768 + brow * 512 + slot * 16);
                acc[n] = MFMA16(afr[ks], bfr, acc[n]);
            }
        }

        __syncthreads();          // ws reads done -> safe to overwrite
        stageW(c + 1);            // DMA next chunk; epilogue covers flight

        const int rowbase = r0 + wid * 16 + (lg << 2);
        #pragma unroll
        for (int n = 0; n < 4; ++n) {
            const int col   = wr0 + n * 16 + l15;
            const float bias = bm[m][col];
            #pragma unroll
            for (int j = 0; j < 4; ++j) {
                const int grow = rowbase + j;
                float ov = acc[n][j] + bias;
                if (m == 0) ov *= QSCALE;         // Q pre-scale (exp2 domain)
                short hv = f2bf(ov);
                if (m == 0)      Qb[(size_t)grow * 256 + col] = hv;
                else if (m == 1) Kb[(size_t)grow * 256 + col] = hv;
                else {
                    int bb = grow >> 12, tt = grow & 4095;
                    VTg[(size_t)bb * (256 * 4096) + (size_t)col * 4096 + tt] = hv;
                }
            }
        }

        asm volatile("s_waitcnt vmcnt(0)" ::: "memory");
        __syncthreads();          // next chunk staged
    }
}

// ---------------------------------------------------------------------------
// Kernel 2: causal flash attention (r22 champion + exp2-domain softmax:
// Q pre-scaled by 1/16*log2e at projection -> no scale mul here, all exps
// are bare v_exp_f32; T13 bound becomes 2^8 = 256).
// ---------------------------------------------------------------------------
__global__ __launch_bounds__(512, 1) void attn_fwd(
    const short* __restrict__ Qb, const short* __restrict__ Kb,
    const short* __restrict__ VTg, float* __restrict__ out)
{
    // [0,65536)        K tiles [par][32 key][256 d], row 512B, slot s at s^(key&15)
    // [65536,131072)   V tiles [par][256 d][32 key], row 64B,  slot s at s^((d>>1)&3)
    // [131072,143360)  Ps: per-wave [16 rows][48 shorts]
    // epilogue overlay: scr [2][32][260] f32 + ms [2][32][2] f32
    __shared__ __attribute__((aligned(16))) char SMEM[143360];
    short* Ps = (short*)(SMEM + 131072);

    const int tid = threadIdx.x;
    const int wid = tid >> 6;          // 0..7
    const int l   = tid & 63;
    const int l15 = l & 15, lg = l >> 4;
    const int rg  = wid >> 2;          // 0..1 : which 16 rows
    const int par = wid & 3;           // kt-tile parity 0..3

    // LPT decode: heaviest row-blocks dispatched first
    const int bid    = blockIdx.x;             // 0..511
    const int rowblk = 127 - (bid >> 2);       // 32-row tiles, heavy first
    const int b      = bid & 3;
    const int nkt    = rowblk + 1;             // 32-key tiles
    const int nsi    = (nkt + 3) >> 2;

    const short* KbB = Kb  + (size_t)b * 4096 * 256;
    const short* VTB = VTg + (size_t)b * (256 * 4096);

    const int qrow_loc = rg * 16 + l15;
    const int qrow     = rowblk * 32 + qrow_loc;

    // Q fragments (B-operand), row = qrow
    short8 qf[8];
    {
        const short* qr = Qb + ((size_t)(b * 4096 + qrow)) * 256 + lg * 8;
        #pragma unroll
        for (int ks = 0; ks < 8; ++ks)
            qf[ks] = *(const short8*)(qr + ks * 32);
    }

    // DMA staging: wave wid<4 -> K[wid&3]; wid>=4 -> V[wid&3]. 16KB/wave.
    auto stage = [&](int si) {
        const int ktt = si * 4 + (wid & 3);
        if (ktt >= nkt) return;
        if (wid < 4) {
            char* lb = SMEM + (wid & 3) * 16384;
            const short* gK = KbB + (size_t)ktt * 32 * 256;
            #pragma unroll
            for (int inst = 0; inst < 16; ++inst) {
                int off  = inst * 1024 + l * 16;            // linear dest byte
                int key  = off >> 9;
                int slot = ((off >> 4) & 31) ^ (key & 15);  // inverse swizzle
                gload16(gK + key * 256 + slot * 8, lb + inst * 1024);
            }
        } else {
            char* lb = SMEM + 65536 + (wid & 3) * 16384;
            const short* gV = VTB + ktt * 32;
            #pragma unroll
            for (int inst = 0; inst < 16; ++inst) {
                int off = inst * 1024 + l * 16;
                int d   = off >> 6;
                int s   = ((off >> 4) & 3) ^ ((d >> 1) & 3);
                gload16(gV + (size_t)d * 4096 + s * 8, lb + inst * 1024);
            }
        }
    };
    stage(0);

    f32x4 o[16] = {};
    float mrow = -INFINITY, srow = 0.f;

    for (int si = 0; si < nsi; ++si) {
        // drain own DMA, then barrier: all tiles in LDS before anyone reads
        asm volatile("s_waitcnt vmcnt(0)" ::: "memory");
        __syncthreads();

        const int kt  = si * 4 + par;
        const bool act = (kt < nkt);
        short8 vf2[4], pb;

        if (act) {
            // ---- S^T = K * Q : lane holds S[qrow=l15][key=tk*16+lg*4+j] ----
            const short* Kt = (const short*)(SMEM + par * 16384);
            f32x4 sA[2] = {};
            __builtin_amdgcn_s_setprio(1);                    // T5
            #pragma unroll
            for (int tk = 0; tk < 2; ++tk) {
                const int key = tk * 16 + l15;
                #pragma unroll
                for (int ks = 0; ks < 8; ++ks) {
                    const int slot = (ks * 4 + lg) ^ l15;
                    short8 kf = *(const short8*)(Kt + key * 256 + slot * 8);
                    sA[tk] = MFMA16(kf, qf[ks], sA[tk]);
                }
            }
            __builtin_amdgcn_s_setprio(0);                    // T5

            // ---- causal mask + per-lane max (S already exp2-scaled) ----
            float pmax = -INFINITY;
            #pragma unroll
            for (int tk = 0; tk < 2; ++tk)
                #pragma unroll
                for (int j4 = 0; j4 < 4; ++j4) {
                    const int key = kt * 32 + tk * 16 + lg * 4 + j4;
                    float v = sA[tk][j4];
                    v = (key > qrow) ? -INFINITY : v;
                    sA[tk][j4] = v;
                    pmax = fmaxf(pmax, v);
                }
            pmax = fmaxf(pmax, __shfl_xor(pmax, 16, 64));
            pmax = fmaxf(pmax, __shfl_xor(pmax, 32, 64));
            // pmax finite whenever act (every row has >=1 unmasked key)

            // T13 defer-max: rescale only when max grew by > 8 (P <= 2^8)
            const bool grow2 = !__all(pmax - mrow <= 8.f);
            float f = 1.f;
            if (grow2) {
                const float mn = fmaxf(mrow, pmax);           // finite
                f = EXP2F(mrow - mn);                         // 0 on first tile
                mrow = mn;
            }

            // P = exp2(s - mrow), packed bf16
            short* Pw = Ps + wid * 768;        // [16][48] shorts
            float ps = 0.f;
            #pragma unroll
            for (int tk = 0; tk < 2; ++tk) {
                float p0 = EXP2F(sA[tk][0] - mrow);
                float p1 = EXP2F(sA[tk][1] - mrow);
                float p2 = EXP2F(sA[tk][2] - mrow);
                float p3 = EXP2F(sA[tk][3] - mrow);
                ps += (p0 + p1) + (p2 + p3);
                unsigned* pw = (unsigned*)(Pw + l15 * 48 + tk * 16 + lg * 4);
                pw[0] = pack2(p0, p1);
                pw[1] = pack2(p2, p3);
            }
            srow = srow * f + ps;

            // rescale O only when the max moved (wave-uniform branch)
            if (grow2) {
                #pragma unroll
                for (int dt = 0; dt < 16; ++dt)
                    #pragma unroll
                    for (int j4 = 0; j4 < 4; ++j4) o[dt][j4] *= f;
            }

            asm volatile("s_waitcnt lgkmcnt(0)" ::: "memory");
            __builtin_amdgcn_sched_barrier(0);

            // B-frag: contiguous keys lg*8..+7 of row l15 (same map as A=V)
            pb = *(const short8*)(Pw + l15 * 48 + lg * 8);

            // ---- PV part 1: dt 0..11 ----
            const short* Vt = (const short*)(SMEM + 65536 + par * 16384);
            __builtin_amdgcn_s_setprio(1);                    // T5
            #pragma unroll
            for (int dt = 0; dt < 12; ++dt) {
                const int d  = dt * 16 + l15;
                const int sx = lg ^ ((d >> 1) & 3);
                short8 va = *(const short8*)(Vt + d * 32 + sx * 8);
                o[dt] = MFMA16(va, pb, o[dt]);
            }
            __builtin_amdgcn_s_setprio(0);                    // T5
            // reads for deferred part
            #pragma unroll
            for (int dt = 12; dt < 16; ++dt) {
                const int d  = dt * 16 + l15;
                const int sx = lg ^ ((d >> 1) & 3);
                vf2[dt - 12] = *(const short8*)(Vt + d * 32 + sx * 8);
            }
        }

        __syncthreads();                 // all LDS reads of this si done
        if (si + 1 < nsi) stage(si + 1); // async DMA overwrite
        __builtin_amdgcn_sched_barrier(0);

        if (act) {
            // ---- PV part 2 (register-only; overlaps DMA issue/flight) ----
            __builtin_amdgcn_s_setprio(1);                    // T5
            #pragma unroll
            for (int dt = 12; dt < 16; ++dt)
                o[dt] = MFMA16(vf2[dt - 12], pb, o[dt]);
            __builtin_amdgcn_s_setprio(0);                    // T5
        }
    }

    // full row sums across the 4 lg lanes of each row
    srow += __shfl_xor(srow, 16, 64);
    srow += __shfl_xor(srow, 32, 64);

    // ---- 4-way par merge via LDS overlay (exp2 domain) ----
    __syncthreads();
    float* scr = (float*)SMEM;                 // [2][32][260] f32 = 66560 B
    float* ms  = (float*)(SMEM + 66560);       // [2][32][2]  f32

    const int rl = rg * 16 + l15;              // 0..31

    // round 1a: par 2,3 dump
    if (par >= 2) {
        const int p = par - 2;
        #pragma unroll
        for (int dt = 0; dt < 16; ++dt)
            *(f32x4*)&scr[p * 8320 + rl * 260 + dt * 16 + lg * 4] = o[dt];
        if (lg == 0) {
            ms[p * 64 + rl * 2 + 0] = mrow;
            ms[p * 64 + rl * 2 + 1] = srow;
        }
    }
    __syncthreads();
    // round 1b: par0 += par2, par1 += par3 (Me guard: both can be -inf)
    if (par < 2) {
        const float m1 = ms[par * 64 + rl * 2 + 0];
        const float s1 = ms[par * 64 + rl * 2 + 1];
        const float M  = fmaxf(mrow, m1);
        const float Me = (M == -INFINITY) ? 0.f : M;   // guard
        const float w0 = EXP2F(mrow - Me);
        const float w1 = EXP2F(m1 - Me);
        srow = srow * w0 + s1 * w1;
        mrow = M;
        #pragma unroll
        for (int dt = 0; dt < 16; ++dt) {
            f32x4 o1 = *(f32x4*)&scr[par * 8320 + rl * 260 + dt * 16 + lg * 4];
            #pragma unroll
            for (int j4 = 0; j4 < 4; ++j4)
                o[dt][j4] = o[dt][j4] * w0 + o1[j4] * w1;
        }
    }
    __syncthreads();
    // round 2a: par1 dumps merged partial
    if (par == 1) {
        #pragma unroll
        for (int dt = 0; dt < 16; ++dt)
            *(f32x4*)&scr[rl * 260 + dt * 16 + lg * 4] = o[dt];
        if (lg == 0) {
            ms[rl * 2 + 0] = mrow;
            ms[rl * 2 + 1] = srow;
        }
    }
    __syncthreads();
    // round 2b: par0 merges, normalizes, stores
    if (par == 0) {
        const float m1 = ms[rl * 2 + 0];
        const float s1 = ms[rl * 2 + 1];
        const float M  = fmaxf(mrow, m1);      // par0 owns tile 0 -> finite
        const float Me = (M == -INFINITY) ? 0.f : M;   // guard anyway
        const float w0 = EXP2F(mrow - Me);
        const float w1 = EXP2F(m1 - Me);
        const float rs = 1.f / (srow * w0 + s1 * w1);
        float* og = out + ((size_t)(b * 4096 + rowblk * 32 + rl)) * 256;
        #pragma unroll
        for (int dt = 0; dt < 16; ++dt) {
            f32x4 o1 = *(f32x4*)&scr[rl * 260 + dt * 16 + lg * 4];
            f32x4 r;
            #pragma unroll
            for (int j4 = 0; j4 < 4; ++j4)
                r[j4] = (o[dt][j4] * w0 + o1[j4] * w1) * rs;
            *(f32x4*)&og[dt * 16 + lg * 4] = r;
        }
    }
}

// ---------------------------------------------------------------------------
extern "C" void kernel_launch(void* const* d_in, const int* in_sizes, int n_in,
                              void* d_out, int out_size, void* d_ws, size_t ws_size,
                              hipStream_t stream) {
    const float* x  = (const float*)d_in[0];
    const float* Wq = (const float*)d_in[1];
    const float* bq = (const float*)d_in[2];
    const float* Wk = (const float*)d_in[3];
    const float* bk = (const float*)d_in[4];
    const float* Wv = (const float*)d_in[5];
    const float* bv = (const float*)d_in[6];

    short* Qb  = (short*)d_ws;                         // 8 MB
    short* Kb  = Qb + (size_t)16384 * 256;             // 8 MB
    short* VTg = Kb + (size_t)16384 * 256;             // 8 MB
    short* Wb  = VTg + (size_t)4 * 256 * 4096;         // 384 KB
    short* xbb = Wb + (size_t)768 * 256;               // 8 MB (fast path only)
    float* out = (float*)d_out;

    // fast path needs Qb+Kb+VTg+Wb+xb = 16,973,824 shorts = 33,947,648 bytes
    const bool fast = ws_size >= (size_t)33947648;

    if (fast) {
        conv2<<<dim3(2144), dim3(256), 0, stream>>>(Wq, Wk, Wv, x, Wb, xbb);
        qkv_proj2<<<dim3(256, 4), dim3(256), 0, stream>>>(xbb, Wb, bq, bk, bv,
                                                          Qb, Kb, VTg);
    } else {
        wconv<<<dim3(96), dim3(256), 0, stream>>>(Wq, Wk, Wv, Wb);
        qkv_proj<<<dim3(256, 4), dim3(256), 0, stream>>>(x, Wb, bq, bk, bv,
                                                         Qb, Kb, VTg);
    }
    attn_fwd<<<dim3(512), dim3(512), 0, stream>>>(Qb, Kb, VTg, out);
}

// Round 24
// 132.073 us; speedup vs baseline: 1.0102x; 1.0102x over previous
//
#include <hip/hip_runtime.h>
#include <hip/hip_bf16.h>

typedef __attribute__((ext_vector_type(8))) short short8;
typedef __attribute__((ext_vector_type(4))) short short4v;
typedef __attribute__((ext_vector_type(4))) float f32x4;

#define MFMA16(a, b, c) __builtin_amdgcn_mfma_f32_16x16x32_bf16(a, b, c, 0, 0, 0)

// round-to-nearest-even f32 -> bf16 bit pattern
__device__ __forceinline__ short f2bf(float f) {
    union { float f; unsigned u; } v; v.f = f;
    unsigned r = v.u + 0x7fffu + ((v.u >> 16) & 1u);
    return (short)(r >> 16);
}
__device__ __forceinline__ unsigned pack2(float lo, float hi) {
    return ((unsigned)(unsigned short)f2bf(hi) << 16) |
           (unsigned)(unsigned short)f2bf(lo);
}
// async global->LDS, 16B/lane; LDS dest = wave-uniform base + lane*16
__device__ __forceinline__ void gload16(const void* g, void* lds) {
    __builtin_amdgcn_global_load_lds(
        (const __attribute__((address_space(1))) unsigned int*)g,
        (__attribute__((address_space(3))) unsigned int*)lds, 16, 0, 0);
}

// ---------------------------------------------------------------------------
// Kernel 0a (fallback): convert [Wq;Wk;Wv] (768x256 f32) to bf16.
// ---------------------------------------------------------------------------
__global__ __launch_bounds__(256) void wconv(
    const float* __restrict__ Wq, const float* __restrict__ Wk,
    const float* __restrict__ Wv, short* __restrict__ Wb)
{
    int e = (blockIdx.x * 256 + threadIdx.x) * 8;
    const float* p = (e < 65536) ? (Wq + e)
                   : (e < 131072) ? (Wk + (e - 65536))
                                  : (Wv + (e - 131072));
    float4 a = *(const float4*)p;
    float4 b = *(const float4*)(p + 4);
    short8 h = { f2bf(a.x), f2bf(a.y), f2bf(a.z), f2bf(a.w),
                 f2bf(b.x), f2bf(b.y), f2bf(b.z), f2bf(b.w) };
    *(short8*)(Wb + e) = h;
}

// ---------------------------------------------------------------------------
// Kernel 0b (fast path): convert W (768x256) AND x (16384x256) f32 -> bf16.
// ---------------------------------------------------------------------------
__global__ __launch_bounds__(256) void conv2(
    const float* __restrict__ Wq, const float* __restrict__ Wk,
    const float* __restrict__ Wv, const float* __restrict__ x,
    short* __restrict__ Wb, short* __restrict__ xb)
{
    const int bid = blockIdx.x;
    if (bid < 96) {
        int e = (bid * 256 + threadIdx.x) * 8;
        const float* p = (e < 65536) ? (Wq + e)
                       : (e < 131072) ? (Wk + (e - 65536))
                                      : (Wv + (e - 131072));
        float4 a = *(const float4*)p;
        float4 b = *(const float4*)(p + 4);
        short8 h = { f2bf(a.x), f2bf(a.y), f2bf(a.z), f2bf(a.w),
                     f2bf(b.x), f2bf(b.y), f2bf(b.z), f2bf(b.w) };
        *(short8*)(Wb + e) = h;
    } else {
        int e = ((bid - 96) * 256 + threadIdx.x) * 8;
        float4 a = *(const float4*)(x + e);
        float4 b = *(const float4*)(x + e + 4);
        short8 h = { f2bf(a.x), f2bf(a.y), f2bf(a.z), f2bf(a.w),
                     f2bf(b.x), f2bf(b.y), f2bf(b.z), f2bf(b.w) };
        *(short8*)(xb + e) = h;
    }
}

// ---------------------------------------------------------------------------
// Kernel 1a (fallback): QKV projection, r15-verified text.
// ---------------------------------------------------------------------------
__global__ __launch_bounds__(256) void qkv_proj(
    const float* __restrict__ x, const short* __restrict__ Wb,
    const float* __restrict__ bq, const float* __restrict__ bk,
    const float* __restrict__ bv,
    short* __restrict__ Qb, short* __restrict__ Kb, short* __restrict__ VTg)
{
    __shared__ short xs[64 * 264];
    __shared__ short wsS[64 * 264];

    const int tid = threadIdx.x;
    const int wid = tid >> 6;
    const int l   = tid & 63;
    const int l15 = l & 15, lg = l >> 4;
    const int r0  = blockIdx.x * 64;
    const int cg  = blockIdx.y;

    {
        const float4* src = (const float4*)(x + (size_t)r0 * 256);
        #pragma unroll
        for (int p = 0; p < 16; ++p) {
            float4 v = src[p * 256 + tid];
            int idx = (p * 256 + tid) * 4;
            int row = idx >> 8, col = idx & 255;
            short4v h = { f2bf(v.x), f2bf(v.y), f2bf(v.z), f2bf(v.w) };
            *(short4v*)&xs[row * 264 + col] = h;
        }
    }

    short8 wreg[8];
    {
        const short8* wsrc = (const short8*)(Wb + (size_t)(cg * 3) * 64 * 256);
        #pragma unroll
        for (int p = 0; p < 8; ++p) wreg[p] = wsrc[p * 256 + tid];
    }
    __syncthreads();

    short8 afr[8];
    {
        const int arow = wid * 16 + l15;
        #pragma unroll
        for (int ks = 0; ks < 8; ++ks)
            afr[ks] = *(const short8*)&xs[arow * 264 + ks * 32 + lg * 8];
    }

    const float* bm[3] = { bq, bk, bv };

    for (int c = 0; c < 3; ++c) {
        const int gc  = cg * 3 + c;
        const int m   = gc >> 2;
        const int wr0 = (gc & 3) * 64;

        #pragma unroll
        for (int p = 0; p < 8; ++p) {
            int idx8 = p * 256 + tid;
            int row = idx8 >> 5, col = (idx8 & 31) * 8;
            *(short8*)&wsS[row * 264 + col] = wreg[p];
        }
        __syncthreads();

        if (c < 2) {
            const short8* wsrc =
                (const short8*)(Wb + (size_t)(gc + 1) * 64 * 256);
            #pragma unroll
            for (int p = 0; p < 8; ++p) wreg[p] = wsrc[p * 256 + tid];
        }

        f32x4 acc[4] = {};
        #pragma unroll
        for (int n = 0; n < 4; ++n) {
            const short* kr = &wsS[(n * 16 + l15) * 264 + lg * 8];
            #pragma unroll
            for (int ks = 0; ks < 8; ++ks) {
                short8 bfr = *(const short8*)(kr + ks * 32);
                acc[n] = MFMA16(afr[ks], bfr, acc[n]);
            }
        }

        const int rowbase = r0 + wid * 16 + (lg << 2);
        #pragma unroll
        for (int n = 0; n < 4; ++n) {
            const int col   = wr0 + n * 16 + l15;
            const float bias = bm[m][col];
            #pragma unroll
            for (int j = 0; j < 4; ++j) {
                const int grow = rowbase + j;
                short hv = f2bf(acc[n][j] + bias);
                if (m == 0)      Qb[(size_t)grow * 256 + col] = hv;
                else if (m == 1) Kb[(size_t)grow * 256 + col] = hv;
                else {
                    int bb = grow >> 12, tt = grow & 4095;
                    VTg[(size_t)bb * (256 * 4096) + (size_t)col * 4096 + tt] = hv;
                }
            }
        }
        __syncthreads();
    }
}

// ---------------------------------------------------------------------------
// Kernel 1b (fast path): QKV projection with DMA staging (r16-verified).
// ---------------------------------------------------------------------------
__global__ __launch_bounds__(256, 2) void qkv_proj2(
    const short* __restrict__ xb, const short* __restrict__ Wb,
    const float* __restrict__ bq, const float* __restrict__ bk,
    const float* __restrict__ bv,
    short* __restrict__ Qb, short* __restrict__ Kb, short* __restrict__ VTg)
{
    // [0,32768)     xs: 64 rows x 512B, 16B slot s stored at s^(row&15)
    // [32768,65536) ws: same layout, current W chunk
    __shared__ __attribute__((aligned(16))) char SM[65536];

    const int tid = threadIdx.x;
    const int wid = tid >> 6;
    const int l   = tid & 63;
    const int l15 = l & 15, lg = l >> 4;
    const int r0  = blockIdx.x * 64;
    const int cg  = blockIdx.y;

    // DMA x tile (32KB): 8 instr/thread
    {
        const short* gx = xb + (size_t)r0 * 256;
        #pragma unroll
        for (int inst = 0; inst < 8; ++inst) {
            int off  = inst * 4096 + wid * 1024 + l * 16;   // linear dest byte
            int row  = off >> 9;
            int slot = ((off >> 4) & 31) ^ (row & 15);      // inverse swizzle
            gload16(gx + row * 256 + slot * 8, SM + inst * 4096 + wid * 1024);
        }
    }
    // DMA W chunk c into ws
    auto stageW = [&](int c) {
        if (c >= 3) return;
        const short* gW = Wb + (size_t)(cg * 3 + c) * 64 * 256;
        #pragma unroll
        for (int inst = 0; inst < 8; ++inst) {
            int off  = inst * 4096 + wid * 1024 + l * 16;
            int row  = off >> 9;
            int slot = ((off >> 4) & 31) ^ (row & 15);
            gload16(gW + row * 256 + slot * 8,
                    SM + 32768 + inst * 4096 + wid * 1024);
        }
    };
    stageW(0);

    asm volatile("s_waitcnt vmcnt(0)" ::: "memory");
    __syncthreads();

    // A-fragments once (full K=256 resident), attn-verified slot formula
    short8 afr[8];
    {
        const int arow = wid * 16 + l15;
        #pragma unroll
        for (int ks = 0; ks < 8; ++ks) {
            const int slot = (ks * 4 + lg) ^ l15;
            afr[ks] = *(const short8*)(SM + arow * 512 + slot * 16);
        }
    }

    const float* bm[3] = { bq, bk, bv };

    for (int c = 0; c < 3; ++c) {
        const int gc  = cg * 3 + c;
        const int m   = gc >> 2;
        const int wr0 = (gc & 3) * 64;

        f32x4 acc[4] = {};
        #pragma unroll
        for (int n = 0; n < 4; ++n) {
            const int brow = n * 16 + l15;
            #pragma unroll
            for (int ks = 0; ks < 8; ++ks) {
                const int slot = (ks * 4 + lg) ^ l15;
                short8 bfr = *(const short8*)(SM + 32768 + brow * 512 + slot * 16);
                acc[n] = MFMA16(afr[ks], bfr, acc[n]);
            }
        }

        __syncthreads();          // ws reads done -> safe to overwrite
        stageW(c + 1);            // DMA next chunk; epilogue covers flight

        const int rowbase = r0 + wid * 16 + (lg << 2);
        #pragma unroll
        for (int n = 0; n < 4; ++n) {
            const int col   = wr0 + n * 16 + l15;
            const float bias = bm[m][col];
            #pragma unroll
            for (int j = 0; j < 4; ++j) {
                const int grow = rowbase + j;
                short hv = f2bf(acc[n][j] + bias);
                if (m == 0)      Qb[(size_t)grow * 256 + col] = hv;
                else if (m == 1) Kb[(size_t)grow * 256 + col] = hv;
                else {
                    int bb = grow >> 12, tt = grow & 4095;
                    VTg[(size_t)bb * (256 * 4096) + (size_t)col * 4096 + tt] = hv;
                }
            }
        }

        asm volatile("s_waitcnt vmcnt(0)" ::: "memory");
        __syncthreads();          // next chunk staged
    }
}

// ---------------------------------------------------------------------------
// Kernel 2: causal flash attention (FINAL champion, 104.7us measured):
//   r11 chassis (512x512, 4-way kt split, K+V global_load_lds staging with
//   XOR-swizzled sources, LPT dispatch, swapped-QK^T per-lane softmax,
//   4-way guarded merge) + T5 setprio + T13 defer-max.
// ---------------------------------------------------------------------------
__global__ __launch_bounds__(512, 1) void attn_fwd(
    const short* __restrict__ Qb, const short* __restrict__ Kb,
    const short* __restrict__ VTg, float* __restrict__ out)
{
    // [0,65536)        K tiles [par][32 key][256 d], row 512B, slot s at s^(key&15)
    // [65536,131072)   V tiles [par][256 d][32 key], row 64B,  slot s at s^((d>>1)&3)
    // [131072,143360)  Ps: per-wave [16 rows][48 shorts]
    // epilogue overlay: scr [2][32][260] f32 + ms [2][32][2] f32
    __shared__ __attribute__((aligned(16))) char SMEM[143360];
    short* Ps = (short*)(SMEM + 131072);

    const int tid = threadIdx.x;
    const int wid = tid >> 6;          // 0..7
    const int l   = tid & 63;
    const int l15 = l & 15, lg = l >> 4;
    const int rg  = wid >> 2;          // 0..1 : which 16 rows
    const int par = wid & 3;           // kt-tile parity 0..3

    // LPT decode: heaviest row-blocks dispatched first
    const int bid    = blockIdx.x;             // 0..511
    const int rowblk = 127 - (bid >> 2);       // 32-row tiles, heavy first
    const int b      = bid & 3;
    const int nkt    = rowblk + 1;             // 32-key tiles
    const int nsi    = (nkt + 3) >> 2;

    const short* KbB = Kb  + (size_t)b * 4096 * 256;
    const short* VTB = VTg + (size_t)b * (256 * 4096);

    const int qrow_loc = rg * 16 + l15;
    const int qrow     = rowblk * 32 + qrow_loc;

    // Q fragments (B-operand), row = qrow
    short8 qf[8];
    {
        const short* qr = Qb + ((size_t)(b * 4096 + qrow)) * 256 + lg * 8;
        #pragma unroll
        for (int ks = 0; ks < 8; ++ks)
            qf[ks] = *(const short8*)(qr + ks * 32);
    }

    // DMA staging: wave wid<4 -> K[wid&3]; wid>=4 -> V[wid&3]. 16KB/wave.
    auto stage = [&](int si) {
        const int ktt = si * 4 + (wid & 3);
        if (ktt >= nkt) return;
        if (wid < 4) {
            char* lb = SMEM + (wid & 3) * 16384;
            const short* gK = KbB + (size_t)ktt * 32 * 256;
            #pragma unroll
            for (int inst = 0; inst < 16; ++inst) {
                int off  = inst * 1024 + l * 16;            // linear dest byte
                int key  = off >> 9;
                int slot = ((off >> 4) & 31) ^ (key & 15);  // inverse swizzle
                gload16(gK + key * 256 + slot * 8, lb + inst * 1024);
            }
        } else {
            char* lb = SMEM + 65536 + (wid & 3) * 16384;
            const short* gV = VTB + ktt * 32;
            #pragma unroll
            for (int inst = 0; inst < 16; ++inst) {
                int off = inst * 1024 + l * 16;
                int d   = off >> 6;
                int s   = ((off >> 4) & 3) ^ ((d >> 1) & 3);
                gload16(gV + (size_t)d * 4096 + s * 8, lb + inst * 1024);
            }
        }
    };
    stage(0);

    f32x4 o[16] = {};
    float mrow = -INFINITY, srow = 0.f;

    for (int si = 0; si < nsi; ++si) {
        // drain own DMA, then barrier: all tiles in LDS before anyone reads
        asm volatile("s_waitcnt vmcnt(0)" ::: "memory");
        __syncthreads();

        const int kt  = si * 4 + par;
        const bool act = (kt < nkt);
        short8 vf2[4], pb;

        if (act) {
            // ---- S^T = K * Q : lane holds S[qrow=l15][key=tk*16+lg*4+j] ----
            const short* Kt = (const short*)(SMEM + par * 16384);
            f32x4 sA[2] = {};
            __builtin_amdgcn_s_setprio(1);                    // T5
            #pragma unroll
            for (int tk = 0; tk < 2; ++tk) {
                const int key = tk * 16 + l15;
                #pragma unroll
                for (int ks = 0; ks < 8; ++ks) {
                    const int slot = (ks * 4 + lg) ^ l15;
                    short8 kf = *(const short8*)(Kt + key * 256 + slot * 8);
                    sA[tk] = MFMA16(kf, qf[ks], sA[tk]);
                }
            }
            __builtin_amdgcn_s_setprio(0);                    // T5

            // ---- scale + causal mask + per-lane softmax ----
            float pmax = -INFINITY;
            #pragma unroll
            for (int tk = 0; tk < 2; ++tk)
                #pragma unroll
                for (int j4 = 0; j4 < 4; ++j4) {
                    const int key = kt * 32 + tk * 16 + lg * 4 + j4;
                    float v = sA[tk][j4] * 0.0625f;       // 1/sqrt(256)
                    v = (key > qrow) ? -INFINITY : v;
                    sA[tk][j4] = v;
                    pmax = fmaxf(pmax, v);
                }
            pmax = fmaxf(pmax, __shfl_xor(pmax, 16, 64));
            pmax = fmaxf(pmax, __shfl_xor(pmax, 32, 64));
            // pmax finite whenever act (every row has >=1 unmasked key)

            // T13 defer-max: rescale only when max grew by > 8 anywhere
            const bool grow2 = !__all(pmax - mrow <= 8.f);
            float f = 1.f;
            if (grow2) {
                const float mn = fmaxf(mrow, pmax);           // finite
                f = __expf(mrow - mn);                        // 0 on first tile
                mrow = mn;
            }

            // P = exp(s - mrow) (bounded by e^8 under defer)
            short* Pw = Ps + wid * 768;        // [16][48] shorts
            float ps = 0.f;
            #pragma unroll
            for (int tk = 0; tk < 2; ++tk) {
                float p0 = __expf(sA[tk][0] - mrow);
                float p1 = __expf(sA[tk][1] - mrow);
                float p2 = __expf(sA[tk][2] - mrow);
                float p3 = __expf(sA[tk][3] - mrow);
                ps += (p0 + p1) + (p2 + p3);
                unsigned* pw = (unsigned*)(Pw + l15 * 48 + tk * 16 + lg * 4);
                pw[0] = pack2(p0, p1);
                pw[1] = pack2(p2, p3);
            }
            srow = srow * f + ps;

            // rescale O only when the max moved (wave-uniform branch)
            if (grow2) {
                #pragma unroll
                for (int dt = 0; dt < 16; ++dt)
                    #pragma unroll
                    for (int j4 = 0; j4 < 4; ++j4) o[dt][j4] *= f;
            }

            asm volatile("s_waitcnt lgkmcnt(0)" ::: "memory");
            __builtin_amdgcn_sched_barrier(0);

            // B-frag: contiguous keys lg*8..+7 of row l15 (same map as A=V)
            pb = *(const short8*)(Pw + l15 * 48 + lg * 8);

            // ---- PV part 1: dt 0..11 ----
            const short* Vt = (const short*)(SMEM + 65536 + par * 16384);
            __builtin_amdgcn_s_setprio(1);                    // T5
            #pragma unroll
            for (int dt = 0; dt < 12; ++dt) {
                const int d  = dt * 16 + l15;
                const int sx = lg ^ ((d >> 1) & 3);
                short8 va = *(const short8*)(Vt + d * 32 + sx * 8);
                o[dt] = MFMA16(va, pb, o[dt]);
            }
            __builtin_amdgcn_s_setprio(0);                    // T5
            // reads for deferred part
            #pragma unroll
            for (int dt = 12; dt < 16; ++dt) {
                const int d  = dt * 16 + l15;
                const int sx = lg ^ ((d >> 1) & 3);
                vf2[dt - 12] = *(const short8*)(Vt + d * 32 + sx * 8);
            }
        }

        __syncthreads();                 // all LDS reads of this si done
        if (si + 1 < nsi) stage(si + 1); // async DMA overwrite
        __builtin_amdgcn_sched_barrier(0);

        if (act) {
            // ---- PV part 2 (register-only; overlaps DMA issue/flight) ----
            __builtin_amdgcn_s_setprio(1);                    // T5
            #pragma unroll
            for (int dt = 12; dt < 16; ++dt)
                o[dt] = MFMA16(vf2[dt - 12], pb, o[dt]);
            __builtin_amdgcn_s_setprio(0);                    // T5
        }
    }

    // full row sums across the 4 lg lanes of each row
    srow += __shfl_xor(srow, 16, 64);
    srow += __shfl_xor(srow, 32, 64);

    // ---- 4-way par merge via LDS overlay (r9-verified, 32-row geometry) ----
    __syncthreads();
    float* scr = (float*)SMEM;                 // [2][32][260] f32 = 66560 B
    float* ms  = (float*)(SMEM + 66560);       // [2][32][2]  f32

    const int rl = rg * 16 + l15;              // 0..31

    // round 1a: par 2,3 dump
    if (par >= 2) {
        const int p = par - 2;
        #pragma unroll
        for (int dt = 0; dt < 16; ++dt)
            *(f32x4*)&scr[p * 8320 + rl * 260 + dt * 16 + lg * 4] = o[dt];
        if (lg == 0) {
            ms[p * 64 + rl * 2 + 0] = mrow;
            ms[p * 64 + rl * 2 + 1] = srow;
        }
    }
    __syncthreads();
    // round 1b: par0 += par2, par1 += par3 (Me guard: both can be -inf)
    if (par < 2) {
        const float m1 = ms[par * 64 + rl * 2 + 0];
        const float s1 = ms[par * 64 + rl * 2 + 1];
        const float M  = fmaxf(mrow, m1);
        const float Me = (M == -INFINITY) ? 0.f : M;   // guard
        const float w0 = __expf(mrow - Me);
        const float w1 = __expf(m1 - Me);
        srow = srow * w0 + s1 * w1;
        mrow = M;
        #pragma unroll
        for (int dt = 0; dt < 16; ++dt) {
            f32x4 o1 = *(f32x4*)&scr[par * 8320 + rl * 260 + dt * 16 + lg * 4];
            #pragma unroll
            for (int j4 = 0; j4 < 4; ++j4)
                o[dt][j4] = o[dt][j4] * w0 + o1[j4] * w1;
        }
    }
    __syncthreads();
    // round 2a: par1 dumps merged partial
    if (par == 1) {
        #pragma unroll
        for (int dt = 0; dt < 16; ++dt)
            *(f32x4*)&scr[rl * 260 + dt * 16 + lg * 4] = o[dt];
        if (lg == 0) {
            ms[rl * 2 + 0] = mrow;
            ms[rl * 2 + 1] = srow;
        }
    }
    __syncthreads();
    // round 2b: par0 merges, normalizes, stores
    if (par == 0) {
        const float m1 = ms[rl * 2 + 0];
        const float s1 = ms[rl * 2 + 1];
        const float M  = fmaxf(mrow, m1);      // par0 owns tile 0 -> finite
        const float Me = (M == -INFINITY) ? 0.f : M;   // guard anyway
        const float w0 = __expf(mrow - Me);
        const float w1 = __expf(m1 - Me);
        const float rs = 1.f / (srow * w0 + s1 * w1);
        float* og = out + ((size_t)(b * 4096 + rowblk * 32 + rl)) * 256;
        #pragma unroll
        for (int dt = 0; dt < 16; ++dt) {
            f32x4 o1 = *(f32x4*)&scr[rl * 260 + dt * 16 + lg * 4];
            f32x4 r;
            #pragma unroll
            for (int j4 = 0; j4 < 4; ++j4)
                r[j4] = (o[dt][j4] * w0 + o1[j4] * w1) * rs;
            *(f32x4*)&og[dt * 16 + lg * 4] = r;
        }
    }
}

// ---------------------------------------------------------------------------
extern "C" void kernel_launch(void* const* d_in, const int* in_sizes, int n_in,
                              void* d_out, int out_size, void* d_ws, size_t ws_size,
                              hipStream_t stream) {
    const float* x  = (const float*)d_in[0];
    const float* Wq = (const float*)d_in[1];
    const float* bq = (const float*)d_in[2];
    const float* Wk = (const float*)d_in[3];
    const float* bk = (const float*)d_in[4];
    const float* Wv = (const float*)d_in[5];
    const float* bv = (const float*)d_in[6];

    short* Qb  = (short*)d_ws;                         // 8 MB
    short* Kb  = Qb + (size_t)16384 * 256;             // 8 MB
    short* VTg = Kb + (size_t)16384 * 256;             // 8 MB
    short* Wb  = VTg + (size_t)4 * 256 * 4096;         // 384 KB
    short* xbb = Wb + (size_t)768 * 256;               // 8 MB (fast path only)
    float* out = (float*)d_out;

    // fast path needs Qb+Kb+VTg+Wb+xb = 16,973,824 shorts = 33,947,648 bytes
    const bool fast = ws_size >= (size_t)33947648;

    if (fast) {
        conv2<<<dim3(2144), dim3(256), 0, stream>>>(Wq, Wk, Wv, x, Wb, xbb);
        qkv_proj2<<<dim3(256, 4), dim3(256), 0, stream>>>(xbb, Wb, bq, bk, bv,
                                                          Qb, Kb, VTg);
    } else {
        wconv<<<dim3(96), dim3(256), 0, stream>>>(Wq, Wk, Wv, Wb);
        qkv_proj<<<dim3(256, 4), dim3(256), 0, stream>>>(x, Wb, bq, bk, bv,
                                                         Qb, Kb, VTg);
    }
    attn_fwd<<<dim3(512), dim3(512), 0, stream>>>(Qb, Kb, VTg, out);
}